// Round 2
// baseline (1973.722 us; speedup 1.0000x reference)
//
#include <hip/hip_runtime.h>
#include <cstdint>

// BDHW_LSTM: B=8, D=64, H=128, W=256, NH=NO=64.
// R2: fused design, ws = 128 MB only (R1's 640 MB ws likely overflowed ws_size -> GPU fault).
//   K1 k_hrec : fused horizontal biLSTM. x@Wih and h@Whh both in-kernel; x staged from img
//               in 16-step chunks (full 64B lines, prefetched). Writes HOUT[m=w*8+b][hh][128].
//   K2 k_vrec : fused vertical biLSTM reading HOUT rows; writes final out[B][128][H][W]
//               directly via LDS retiming (float4 over w-quad, 8 hh-steps buffered).
// Gate order i,f,g,o (PyTorch). All fp32.

__device__ __forceinline__ float sigm(float x) { return 1.0f / (1.0f + __expf(-x)); }
__device__ __forceinline__ float tanh_(float x) { float e = __expf(2.0f * x); return 1.0f - 2.0f / (e + 1.0f); }

// ---------------- K1: fused horizontal recurrence ----------------
// grid 512 = rowgroup(256) x dir(2); block 256. 4 rows/block (same hh, bb0..bb0+3).
// thread t = gate t (256 gates/dir); Wih row + Whh row in VGPRs (128 regs).
// T=256 steps; x chunked 16 steps: thread (rr=t>>6, d=t&63) fetches img[bb0+rr][d][hh][w0:w0+16]
// = one 64B line; next chunk prefetched into regs during current chunk's 16 steps.
__global__ __launch_bounds__(256) void k_hrec(
    const float* __restrict__ img,
    const float* __restrict__ wihf, const float* __restrict__ whhf,
    const float* __restrict__ bif,  const float* __restrict__ bhf,
    const float* __restrict__ wihb, const float* __restrict__ whhb,
    const float* __restrict__ bib,  const float* __restrict__ bhb,
    float* __restrict__ hout)
{
    __shared__ __align__(16) float xs[16 * 4 * 64];   // [wi][rr][d] 16 KB
    __shared__ __align__(16) float hsm[4 * 64];       // [rr][j]
    __shared__ float pre[4 * 256];                    // [rr][gate]
    const int t   = threadIdx.x;
    const int dir = blockIdx.x & 1;
    const int r0  = (blockIdx.x >> 1) * 4;   // base row n = hh*8+bb
    const int hh  = r0 >> 3;
    const int bb0 = r0 & 7;                  // 0 or 4
    const float* Wih = dir ? wihb : wihf;
    const float* Whh = dir ? whhb : whhf;

    float wx[64], wh[64];
    #pragma unroll
    for (int q = 0; q < 16; ++q) {
        const float4 a = *(const float4*)(Wih + t * 64 + q * 4);
        const float4 b = *(const float4*)(Whh + t * 64 + q * 4);
        wx[4 * q] = a.x; wx[4 * q + 1] = a.y; wx[4 * q + 2] = a.z; wx[4 * q + 3] = a.w;
        wh[4 * q] = b.x; wh[4 * q + 1] = b.y; wh[4 * q + 2] = b.z; wh[4 * q + 3] = b.w;
    }
    const float bsum = (dir ? bib : bif)[t] + (dir ? bhb : bhf)[t];

    const int rr_l = t >> 6, dl = t & 63;
    const float* ibase = img + (((size_t)((bb0 + rr_l) * 64 + dl) * 128 + hh) * 256);
    // chunk ck covers w in [w0, w0+15], w0 = dir ? 256-16*(ck+1) : 16*ck
    float4 cr0, cr1, cr2, cr3;
    {
        const float* p = ibase + (dir ? 240 : 0);
        cr0 = *(const float4*)(p);     cr1 = *(const float4*)(p + 4);
        cr2 = *(const float4*)(p + 8); cr3 = *(const float4*)(p + 12);
    }
    hsm[t] = 0.0f;
    float c = 0.0f;
    __syncthreads();

    for (int s = 0; s < 256; ++s) {
        const int ck = s >> 4;
        const int w0c = dir ? (256 - 16 * (ck + 1)) : (16 * ck);
        if ((s & 15) == 0) {
            // stage held chunk into xs (prev step's end-barrier guarantees no readers)
            const float v[16] = { cr0.x, cr0.y, cr0.z, cr0.w, cr1.x, cr1.y, cr1.z, cr1.w,
                                  cr2.x, cr2.y, cr2.z, cr2.w, cr3.x, cr3.y, cr3.z, cr3.w };
            #pragma unroll
            for (int wi = 0; wi < 16; ++wi)
                xs[(wi * 4 + rr_l) * 64 + dl] = v[wi];
            if (ck + 1 < 16) {   // prefetch next chunk (16 steps of latency to hide)
                const float* p = ibase + (dir ? (256 - 16 * (ck + 2)) : (16 * (ck + 1)));
                cr0 = *(const float4*)(p);     cr1 = *(const float4*)(p + 4);
                cr2 = *(const float4*)(p + 8); cr3 = *(const float4*)(p + 12);
            }
            __syncthreads();
        }
        const int w  = dir ? (255 - s) : s;
        const int wi = w - w0c;
        const float* xr = xs + wi * 256;     // [rr][d]

        float a0 = 0.f, a1 = 0.f, a2 = 0.f, a3 = 0.f;
        #pragma unroll
        for (int q = 0; q < 16; ++q) {
            const float u0 = wh[4 * q], u1 = wh[4 * q + 1], u2 = wh[4 * q + 2], u3 = wh[4 * q + 3];
            const float y0 = wx[4 * q], y1 = wx[4 * q + 1], y2 = wx[4 * q + 2], y3 = wx[4 * q + 3];
            {   const float4 h0 = *(const float4*)(hsm + 0   + 4 * q);
                const float4 x0 = *(const float4*)(xr  + 0   + 4 * q);
                a0 += h0.x*u0 + h0.y*u1 + h0.z*u2 + h0.w*u3 + x0.x*y0 + x0.y*y1 + x0.z*y2 + x0.w*y3; }
            {   const float4 h1 = *(const float4*)(hsm + 64  + 4 * q);
                const float4 x1 = *(const float4*)(xr  + 64  + 4 * q);
                a1 += h1.x*u0 + h1.y*u1 + h1.z*u2 + h1.w*u3 + x1.x*y0 + x1.y*y1 + x1.z*y2 + x1.w*y3; }
            {   const float4 h2 = *(const float4*)(hsm + 128 + 4 * q);
                const float4 x2 = *(const float4*)(xr  + 128 + 4 * q);
                a2 += h2.x*u0 + h2.y*u1 + h2.z*u2 + h2.w*u3 + x2.x*y0 + x2.y*y1 + x2.z*y2 + x2.w*y3; }
            {   const float4 h3 = *(const float4*)(hsm + 192 + 4 * q);
                const float4 x3 = *(const float4*)(xr  + 192 + 4 * q);
                a3 += h3.x*u0 + h3.y*u1 + h3.z*u2 + h3.w*u3 + x3.x*y0 + x3.y*y1 + x3.z*y2 + x3.w*y3; }
        }
        pre[0 * 256 + t] = a0 + bsum;
        pre[1 * 256 + t] = a1 + bsum;
        pre[2 * 256 + t] = a2 + bsum;
        pre[3 * 256 + t] = a3 + bsum;
        __syncthreads();
        {   // cell update: t = rr*64+jj owns one cell
            const int rr = t >> 6, jj = t & 63;
            const float gi = pre[rr * 256 + jj];
            const float gf = pre[rr * 256 + 64 + jj];
            const float gg = pre[rr * 256 + 128 + jj];
            const float go = pre[rr * 256 + 192 + jj];
            c = sigm(gf) * c + sigm(gi) * tanh_(gg);
            const float hn = sigm(go) * tanh_(c);
            hsm[t] = hn;
            // HOUT[m=w*8+bb][hh][dir*64+jj], coalesced 256B per wave
            hout[((size_t)(w * 8 + bb0 + rr) << 14) + (hh << 7) + (dir << 6) + jj] = hn;
        }
        __syncthreads();
    }
}

// ---------------- K2: fused vertical recurrence + direct output ----------------
// grid 1024 = group(512) x dir(2); block 512. 4 rows/block: m=(w0+i)*8+b, same b, w-quad.
// thread (half=t>>8, gt=t&255): half0 holds Wih[gt][0:64]+Whh[gt][0:32], half1 the rest.
// Partials combined in LDS. Output buffered 8 hh-steps in LDS, flushed as float4 over w-quad.
__global__ __launch_bounds__(512) void k_vrec(
    const float* __restrict__ hout,
    const float* __restrict__ wihf, const float* __restrict__ whhf,
    const float* __restrict__ bif,  const float* __restrict__ bhf,
    const float* __restrict__ wihb, const float* __restrict__ whhb,
    const float* __restrict__ bib,  const float* __restrict__ bhb,
    float* __restrict__ outp)
{
    __shared__ __align__(16) float xh[4 * 192];   // per row: [0:128]=x, [128:192]=h
    __shared__ float ps[4 * 256];                 // partial -> pre
    __shared__ float ob[8 * 4 * 64];              // [ci][rr][j] output retiming
    const int t    = threadIdx.x;       // 0..511
    const int dir  = blockIdx.x & 1;
    const int g    = blockIdx.x >> 1;   // 0..511
    const int b    = g & 7;
    const int w0   = (g >> 3) * 4;
    const int half = t >> 8;
    const int gt   = t & 255;
    const float* Wih = dir ? wihb : wihf;
    const float* Whh = dir ? whhb : whhf;

    float wx[64], wh[32];
    #pragma unroll
    for (int q = 0; q < 16; ++q) {
        const float4 a = *(const float4*)(Wih + gt * 128 + half * 64 + q * 4);
        wx[4 * q] = a.x; wx[4 * q + 1] = a.y; wx[4 * q + 2] = a.z; wx[4 * q + 3] = a.w;
    }
    #pragma unroll
    for (int q = 0; q < 8; ++q) {
        const float4 a = *(const float4*)(Whh + gt * 64 + half * 32 + q * 4);
        wh[4 * q] = a.x; wh[4 * q + 1] = a.y; wh[4 * q + 2] = a.z; wh[4 * q + 3] = a.w;
    }
    const float bsum = (dir ? bib : bif)[gt] + (dir ? bhb : bhf)[gt];

    const int rr_x = t >> 7, cx = t & 127;
    const size_t xbase = ((size_t)((w0 + rr_x) * 8 + b) << 14) + cx;   // + hh*128 per step
    float c = 0.0f;

    float xreg = hout[xbase + ((size_t)(dir ? 127 : 0) << 7)];
    if (t < 256) xh[(t >> 6) * 192 + 128 + (t & 63)] = 0.0f;
    xh[rr_x * 192 + cx] = xreg;
    __syncthreads();

    for (int s = 0; s < 128; ++s) {
        const int sn = (s + 1 < 128) ? (s + 1) : s;
        const int hh_next = dir ? (127 - sn) : sn;
        // ---- A: partials + next-x prefetch ----
        const float xnext = hout[xbase + ((size_t)hh_next << 7)];
        float acc[4] = { 0.f, 0.f, 0.f, 0.f };
        const int xo = half * 64, ho = 128 + half * 32;
        #pragma unroll
        for (int q = 0; q < 16; ++q) {
            const float y0 = wx[4 * q], y1 = wx[4 * q + 1], y2 = wx[4 * q + 2], y3 = wx[4 * q + 3];
            #pragma unroll
            for (int r = 0; r < 4; ++r) {
                const float4 xv = *(const float4*)(xh + r * 192 + xo + 4 * q);
                acc[r] += xv.x * y0 + xv.y * y1 + xv.z * y2 + xv.w * y3;
            }
        }
        #pragma unroll
        for (int q = 0; q < 8; ++q) {
            const float u0 = wh[4 * q], u1 = wh[4 * q + 1], u2 = wh[4 * q + 2], u3 = wh[4 * q + 3];
            #pragma unroll
            for (int r = 0; r < 4; ++r) {
                const float4 hv = *(const float4*)(xh + r * 192 + ho + 4 * q);
                acc[r] += hv.x * u0 + hv.y * u1 + hv.z * u2 + hv.w * u3;
            }
        }
        if (half) {
            #pragma unroll
            for (int r = 0; r < 4; ++r) ps[r * 256 + gt] = acc[r];
        }
        __syncthreads();
        // ---- B: combine partials; publish next x ----
        if (!half) {
            #pragma unroll
            for (int r = 0; r < 4; ++r) ps[r * 256 + gt] += acc[r] + bsum;
        }
        xh[rr_x * 192 + cx] = xnext;
        __syncthreads();
        // ---- C: cell update ----
        if (t < 256) {
            const int rr = t >> 6, jj = t & 63;
            const float gi = ps[rr * 256 + jj];
            const float gf = ps[rr * 256 + 64 + jj];
            const float gg = ps[rr * 256 + 128 + jj];
            const float go = ps[rr * 256 + 192 + jj];
            c = sigm(gf) * c + sigm(gi) * tanh_(gg);
            const float hn = sigm(go) * tanh_(c);
            xh[rr * 192 + 128 + jj] = hn;
            ob[((s & 7) * 4 + rr) * 64 + jj] = hn;
        }
        __syncthreads();
        if ((s & 7) == 7) {   // flush 8 hh-steps; safe: next ob write is after next sync2
            const int hhc = t >> 6;      // 0..7
            const int j   = t & 63;
            const int sB  = (s & ~7) + hhc;
            const int hhF = dir ? (127 - sB) : sB;
            float4 v;
            v.x = ob[(hhc * 4 + 0) * 64 + j];
            v.y = ob[(hhc * 4 + 1) * 64 + j];
            v.z = ob[(hhc * 4 + 2) * 64 + j];
            v.w = ob[(hhc * 4 + 3) * 64 + j];
            *(float4*)(outp + (((size_t)(b * 128 + (dir << 6) + j) * 128 + hhF) << 8) + w0) = v;
        }
    }
}

extern "C" void kernel_launch(void* const* d_in, const int* in_sizes, int n_in,
                              void* d_out, int out_size, void* d_ws, size_t ws_size,
                              hipStream_t stream)
{
    const float* img   = (const float*)d_in[0];
    const float* hWihF = (const float*)d_in[1];
    const float* hWhhF = (const float*)d_in[2];
    const float* hBiF  = (const float*)d_in[3];
    const float* hBhF  = (const float*)d_in[4];
    const float* hWihB = (const float*)d_in[5];
    const float* hWhhB = (const float*)d_in[6];
    const float* hBiB  = (const float*)d_in[7];
    const float* hBhB  = (const float*)d_in[8];
    const float* vWihF = (const float*)d_in[9];
    const float* vWhhF = (const float*)d_in[10];
    const float* vBiF  = (const float*)d_in[11];
    const float* vBhF  = (const float*)d_in[12];
    const float* vWihB = (const float*)d_in[13];
    const float* vWhhB = (const float*)d_in[14];
    const float* vBiB  = (const float*)d_in[15];
    const float* vBhB  = (const float*)d_in[16];

    float* HOUT = (float*)d_ws;   // 2048 * 128 * 128 f32 = 128 MB (only ws use)

    k_hrec<<<512, 256, 0, stream>>>(img, hWihF, hWhhF, hBiF, hBhF,
                                    hWihB, hWhhB, hBiB, hBhB, HOUT);
    k_vrec<<<1024, 512, 0, stream>>>(HOUT, vWihF, vWhhF, vBiF, vBhF,
                                     vWihB, vWhhB, vBiB, vBhB, (float*)d_out);

    (void)in_sizes; (void)n_in; (void)out_size; (void)ws_size;
}

// Round 3
// 709.840 us; speedup vs baseline: 2.7805x; 2.7805x over previous
//
#include <hip/hip_runtime.h>
#include <cstdint>

// BDHW_LSTM R3: MFMA fp16 recurrence. B=8, D=64, H=128, W=256, NH=NO=64.
//  K0 k_xpose: img f32 [b][d][hh][w] -> XT fp16 [b][hh][w][d]            (32 MB ws)
//  K1 k_hrec : fused horizontal biLSTM, MFMA 16x16x32_f16, M=8 rows (8 hh, 1 b),
//              K=128 (64 x + 64 h), N=256 gates. HOUT fp16 [hh][b][w][128] (64 MB ws)
//  K2 k_vrec : fused vertical biLSTM, M=8 rows (8 w, 1 b), K=192 (128 x + 64 h),
//              N=256. Writes final out f32 [b][ch][hh][w] via float4 (w-contig).
// A=[x||h] staged in LDS in MFMA-fragment order (lane-contiguous 16B): element (m,k):
//   lane l = ((k>>3)&3)*16 + m, LDS fp16 idx = (k>>5)*512 + l*8 + (k&7).
// C layout (m89): col=lane&15 (gate within N-tile), row=(lane>>4)*4+reg.
// Wave wv owns N-tiles {wv, wv+4, wv+8, wv+12} = gates wv*16+col for i,f,g,o
// -> gate nonlinearity fully in-lane. Gate order i,f,g,o (PyTorch).

typedef _Float16 half8_t __attribute__((ext_vector_type(8)));
typedef float f32x4_t __attribute__((ext_vector_type(4)));

__device__ __forceinline__ float sigm(float x) { return 1.0f / (1.0f + __expf(-x)); }
__device__ __forceinline__ float tanh_(float x) { float e = __expf(2.0f * x); return 1.0f - 2.0f / (e + 1.0f); }

__device__ __forceinline__ half8_t load_w8(const float* p) {
    const float4 a = *(const float4*)p;
    const float4 b = *(const float4*)(p + 4);
    half8_t r;
    r[0] = (_Float16)a.x; r[1] = (_Float16)a.y; r[2] = (_Float16)a.z; r[3] = (_Float16)a.w;
    r[4] = (_Float16)b.x; r[5] = (_Float16)b.y; r[6] = (_Float16)b.z; r[7] = (_Float16)b.w;
    return r;
}

// ---------------- K0: img transpose to fp16 [b][hh][w][d] ----------------
__global__ __launch_bounds__(256) void k_xpose(const float* __restrict__ img, _Float16* __restrict__ xt)
{
    __shared__ float Ts[64 * 65];
    const int t  = threadIdx.x;
    const int wt = blockIdx.x & 3;
    const int hh = (blockIdx.x >> 2) & 127;
    const int b  = blockIdx.x >> 9;
    {
        const int d  = t >> 2;
        const int wq = (t & 3) * 16;
        const float* p = img + (((size_t)(b * 64 + d) * 128 + hh) * 256 + wt * 64 + wq);
        #pragma unroll
        for (int i = 0; i < 4; ++i) {
            const float4 v = *(const float4*)(p + i * 4);
            Ts[d * 65 + wq + i * 4 + 0] = v.x;
            Ts[d * 65 + wq + i * 4 + 1] = v.y;
            Ts[d * 65 + wq + i * 4 + 2] = v.z;
            Ts[d * 65 + wq + i * 4 + 3] = v.w;
        }
    }
    __syncthreads();
    const int wl = t >> 2;
    const int dq = (t & 3) * 16;
    half8_t o0, o1;
    #pragma unroll
    for (int i = 0; i < 8; ++i) o0[i] = (_Float16)Ts[(dq + i) * 65 + wl];
    #pragma unroll
    for (int i = 0; i < 8; ++i) o1[i] = (_Float16)Ts[(dq + 8 + i) * 65 + wl];
    _Float16* dst = xt + ((size_t)((b * 128 + hh) * 256 + wt * 64 + wl) << 6) + dq;
    *(half8_t*)(dst)     = o0;
    *(half8_t*)(dst + 8) = o1;
}

// ---------------- K1: horizontal biLSTM (MFMA) ----------------
// grid 256 = (b(8) x hh-octet(16))(128) x dir(2); block 256 (4 waves).
__global__ __launch_bounds__(256) void k_hrec(
    const _Float16* __restrict__ xt,
    const float* __restrict__ wihf, const float* __restrict__ whhf,
    const float* __restrict__ bif,  const float* __restrict__ bhf,
    const float* __restrict__ wihb, const float* __restrict__ whhb,
    const float* __restrict__ bib,  const float* __restrict__ bhb,
    _Float16* __restrict__ hout)
{
    __shared__ __align__(16) _Float16 Afrag[4 * 512];   // 4 KB: ktiles 0,1=x(d), 2,3=h
    __shared__ __align__(16) _Float16 bufC[16 * 8 * 64]; // 16 KB retime
    const int t   = threadIdx.x;
    const int dir = blockIdx.x & 1;
    const int g   = blockIdx.x >> 1;       // 0..127
    const int b   = g & 7;
    const int hh0 = (g >> 3) * 8;
    const int wv  = t >> 6;
    const int l   = t & 63;
    const float* Wih = dir ? wihb : wihf;
    const float* Whh = dir ? whhb : whhf;
    const float* Bi  = dir ? bib  : bif;
    const float* Bh  = dir ? bhb  : bhf;

    // B-frags: Bf[p][kt], gate = p*64 + wv*16 + (l&15), k = kt*32 + (l>>4)*8 + j
    half8_t Bf[4][4];
    float bias[4];
    #pragma unroll
    for (int p = 0; p < 4; ++p) {
        const int gate = p * 64 + wv * 16 + (l & 15);
        bias[p] = Bi[gate] + Bh[gate];
        #pragma unroll
        for (int kt = 0; kt < 4; ++kt) {
            const int k0 = kt * 32 + (l >> 4) * 8;
            const float* src = (kt < 2) ? (Wih + gate * 64 + k0) : (Whh + gate * 64 + (k0 - 64));
            Bf[p][kt] = load_w8(src);
        }
    }
    for (int i = t; i < 2048; i += 256) Afrag[i] = (_Float16)0.0f;
    __syncthreads();

    // x staging: t<64: m = t>>3 (row = hh0+m), part = t&7 (d-octet)
    const int xm = t >> 3, xp = t & 7;
    const _Float16* xbase = xt + ((size_t)(b * 128 + hh0 + xm) << 14) + xp * 8;  // + w*64
    _Float16* xdst = Afrag + (xp >> 2) * 512 + ((xp & 3) * 16 + xm) * 8;
    if (t < 64) {
        const int w_first = dir ? 255 : 0;
        *(half8_t*)xdst = *(const half8_t*)(xbase + (w_first << 6));
    }
    __syncthreads();

    float c[4] = {0.f, 0.f, 0.f, 0.f};
    const int col = l & 15;
    const int rq  = l >> 4;          // row quad; active rows need rq<2
    const int jg  = wv * 16 + col;   // gate 0..63
    // h-frag write coords: k = 64 + jg
    const int hkt = 2 + (jg >> 5);
    const int hbase = hkt * 512 + (((jg >> 3) & 3) * 16) * 8 + (jg & 7);

    for (int s = 0; s < 256; ++s) {
        const int w  = dir ? (255 - s) : s;
        const int sn = (s + 1 < 256) ? (s + 1) : s;
        const int wn = dir ? (255 - sn) : sn;
        half8_t xr;
        if (t < 64) xr = *(const half8_t*)(xbase + (wn << 6));   // prefetch next x

        half8_t A0 = *(const half8_t*)(Afrag + 0 * 512 + l * 8);
        half8_t A1 = *(const half8_t*)(Afrag + 1 * 512 + l * 8);
        half8_t A2 = *(const half8_t*)(Afrag + 2 * 512 + l * 8);
        half8_t A3 = *(const half8_t*)(Afrag + 3 * 512 + l * 8);

        f32x4_t acc[4];
        #pragma unroll
        for (int p = 0; p < 4; ++p) {
            f32x4_t a = {0.f, 0.f, 0.f, 0.f};
            a = __builtin_amdgcn_mfma_f32_16x16x32_f16(A0, Bf[p][0], a, 0, 0, 0);
            a = __builtin_amdgcn_mfma_f32_16x16x32_f16(A1, Bf[p][1], a, 0, 0, 0);
            a = __builtin_amdgcn_mfma_f32_16x16x32_f16(A2, Bf[p][2], a, 0, 0, 0);
            a = __builtin_amdgcn_mfma_f32_16x16x32_f16(A3, Bf[p][3], a, 0, 0, 0);
            acc[p] = a;
        }
        float hv[4];
        #pragma unroll
        for (int r = 0; r < 4; ++r) {
            const float gi = acc[0][r] + bias[0];
            const float gf = acc[1][r] + bias[1];
            const float gg = acc[2][r] + bias[2];
            const float go = acc[3][r] + bias[3];
            c[r] = sigm(gf) * c[r] + sigm(gi) * tanh_(gg);
            hv[r] = sigm(go) * tanh_(c[r]);
        }
        __syncthreads();   // barrier1: all frag reads done
        if (rq < 2) {      // active rows 0..7
            #pragma unroll
            for (int r = 0; r < 4; ++r) {
                const int m = rq * 4 + r;
                Afrag[hbase + m * 8] = (_Float16)hv[r];
                bufC[((w & 15) * 8 + m) * 64 + jg] = (_Float16)hv[r];
            }
        }
        if (t < 64) *(half8_t*)xdst = xr;
        __syncthreads();   // barrier2: writes visible
        if ((s & 15) == 15) {   // flush 16-w chunk (reads complete before next barrier1)
            const int wc0  = w & ~15;
            const int fm   = t >> 5;          // 0..7
            const int fwi  = (t >> 1) & 15;   // 0..15
            const int fhal = t & 1;
            const _Float16* src = bufC + (fwi * 8 + fm) * 64 + fhal * 32;
            _Float16* dst = hout + ((size_t)(((hh0 + fm) * 8 + b) * 256 + wc0 + fwi) << 7)
                          + dir * 64 + fhal * 32;
            #pragma unroll
            for (int i = 0; i < 4; ++i)
                *(half8_t*)(dst + i * 8) = *(const half8_t*)(src + i * 8);
        }
    }
}

// ---------------- K2: vertical biLSTM (MFMA) + direct output ----------------
// grid 512 = (b(8) x w-octet(32))(256) x dir(2); block 256 (4 waves). T=128.
__global__ __launch_bounds__(256) void k_vrec(
    const _Float16* __restrict__ hout,
    const float* __restrict__ wihf, const float* __restrict__ whhf,
    const float* __restrict__ bif,  const float* __restrict__ bhf,
    const float* __restrict__ wihb, const float* __restrict__ whhb,
    const float* __restrict__ bib,  const float* __restrict__ bhb,
    float* __restrict__ outp)
{
    __shared__ __align__(16) _Float16 Afrag[6 * 512];   // 6 KB: ktiles 0..3=x(128ch), 4,5=h
    const int t   = threadIdx.x;
    const int dir = blockIdx.x & 1;
    const int g   = blockIdx.x >> 1;       // 0..255
    const int b   = g & 7;
    const int w0  = (g >> 3) * 8;
    const int wv  = t >> 6;
    const int l   = t & 63;
    const float* Wih = dir ? wihb : wihf;
    const float* Whh = dir ? whhb : whhf;
    const float* Bi  = dir ? bib  : bif;
    const float* Bh  = dir ? bhb  : bhf;

    half8_t Bf[4][6];
    float bias[4];
    #pragma unroll
    for (int p = 0; p < 4; ++p) {
        const int gate = p * 64 + wv * 16 + (l & 15);
        bias[p] = Bi[gate] + Bh[gate];
        #pragma unroll
        for (int kt = 0; kt < 6; ++kt) {
            const int k0 = kt * 32 + (l >> 4) * 8;
            const float* src = (kt < 4) ? (Wih + gate * 128 + k0) : (Whh + gate * 64 + (k0 - 128));
            Bf[p][kt] = load_w8(src);
        }
    }
    for (int i = t; i < 3072; i += 256) Afrag[i] = (_Float16)0.0f;
    __syncthreads();

    // x staging: t<128: m = t>>4 (row = w0+m), part = t&15 (ch-octet)
    const int xm = t >> 4, xp = t & 15;
    const _Float16* xbase = hout + ((size_t)(b * 256 + w0 + xm) << 7) + xp * 8;  // + hh*(8*256*128)
    _Float16* xdst = Afrag + (xp >> 2) * 512 + ((xp & 3) * 16 + xm) * 8;
    if (t < 128) {
        const int hh_first = dir ? 127 : 0;
        *(half8_t*)xdst = *(const half8_t*)(xbase + ((size_t)hh_first << 18));
    }
    __syncthreads();

    float c[4] = {0.f, 0.f, 0.f, 0.f};
    const int col = l & 15;
    const int rq  = l >> 4;
    const int jg  = wv * 16 + col;
    const int hkt = 4 + (jg >> 5);
    const int hbase = hkt * 512 + (((jg >> 3) & 3) * 16) * 8 + (jg & 7);
    const int ch  = dir * 64 + jg;

    for (int s = 0; s < 128; ++s) {
        const int hh = dir ? (127 - s) : s;
        const int sn = (s + 1 < 128) ? (s + 1) : s;
        const int hn = dir ? (127 - sn) : sn;
        half8_t xr;
        if (t < 128) xr = *(const half8_t*)(xbase + ((size_t)hn << 18));

        half8_t A0 = *(const half8_t*)(Afrag + 0 * 512 + l * 8);
        half8_t A1 = *(const half8_t*)(Afrag + 1 * 512 + l * 8);
        half8_t A2 = *(const half8_t*)(Afrag + 2 * 512 + l * 8);
        half8_t A3 = *(const half8_t*)(Afrag + 3 * 512 + l * 8);
        half8_t A4 = *(const half8_t*)(Afrag + 4 * 512 + l * 8);
        half8_t A5 = *(const half8_t*)(Afrag + 5 * 512 + l * 8);

        f32x4_t acc[4];
        #pragma unroll
        for (int p = 0; p < 4; ++p) {
            f32x4_t a = {0.f, 0.f, 0.f, 0.f};
            a = __builtin_amdgcn_mfma_f32_16x16x32_f16(A0, Bf[p][0], a, 0, 0, 0);
            a = __builtin_amdgcn_mfma_f32_16x16x32_f16(A1, Bf[p][1], a, 0, 0, 0);
            a = __builtin_amdgcn_mfma_f32_16x16x32_f16(A2, Bf[p][2], a, 0, 0, 0);
            a = __builtin_amdgcn_mfma_f32_16x16x32_f16(A3, Bf[p][3], a, 0, 0, 0);
            a = __builtin_amdgcn_mfma_f32_16x16x32_f16(A4, Bf[p][4], a, 0, 0, 0);
            a = __builtin_amdgcn_mfma_f32_16x16x32_f16(A5, Bf[p][5], a, 0, 0, 0);
            acc[p] = a;
        }
        float hv[4];
        #pragma unroll
        for (int r = 0; r < 4; ++r) {
            const float gi = acc[0][r] + bias[0];
            const float gf = acc[1][r] + bias[1];
            const float gg = acc[2][r] + bias[2];
            const float go = acc[3][r] + bias[3];
            c[r] = sigm(gf) * c[r] + sigm(gi) * tanh_(gg);
            hv[r] = sigm(go) * tanh_(c[r]);
        }
        if (rq < 2) {   // direct output: w-contiguous float4
            float4 v = make_float4(hv[0], hv[1], hv[2], hv[3]);
            *(float4*)(outp + ((size_t)(b * 128 + ch) * 128 + hh) * 256 + w0 + rq * 4) = v;
        }
        __syncthreads();   // barrier1
        if (rq < 2) {
            #pragma unroll
            for (int r = 0; r < 4; ++r)
                Afrag[hbase + (rq * 4 + r) * 8] = (_Float16)hv[r];
        }
        if (t < 128) *(half8_t*)xdst = xr;
        __syncthreads();   // barrier2
    }
}

extern "C" void kernel_launch(void* const* d_in, const int* in_sizes, int n_in,
                              void* d_out, int out_size, void* d_ws, size_t ws_size,
                              hipStream_t stream)
{
    const float* img   = (const float*)d_in[0];
    const float* hWihF = (const float*)d_in[1];
    const float* hWhhF = (const float*)d_in[2];
    const float* hBiF  = (const float*)d_in[3];
    const float* hBhF  = (const float*)d_in[4];
    const float* hWihB = (const float*)d_in[5];
    const float* hWhhB = (const float*)d_in[6];
    const float* hBiB  = (const float*)d_in[7];
    const float* hBhB  = (const float*)d_in[8];
    const float* vWihF = (const float*)d_in[9];
    const float* vWhhF = (const float*)d_in[10];
    const float* vBiF  = (const float*)d_in[11];
    const float* vBhF  = (const float*)d_in[12];
    const float* vWihB = (const float*)d_in[13];
    const float* vWhhB = (const float*)d_in[14];
    const float* vBiB  = (const float*)d_in[15];
    const float* vBhB  = (const float*)d_in[16];

    _Float16* XT   = (_Float16*)d_ws;                             // 32 MB
    _Float16* HOUT = (_Float16*)((char*)d_ws + (size_t)33554432); // 64 MB

    k_xpose<<<4096, 256, 0, stream>>>(img, XT);
    k_hrec<<<256, 256, 0, stream>>>(XT, hWihF, hWhhF, hBiF, hBhF,
                                    hWihB, hWhhB, hBiB, hBhB, HOUT);
    k_vrec<<<512, 256, 0, stream>>>(HOUT, vWihF, vWhhF, vBiF, vBhF,
                                    vWihB, vWhhB, vBiB, vBhB, (float*)d_out);

    (void)in_sizes; (void)n_in; (void)out_size; (void)ws_size;
}